// Round 3
// baseline (7057.359 us; speedup 1.0000x reference)
//
#include <hip/hip_runtime.h>
#include <hip/hip_bf16.h>
#include <stdint.h>

// LSTM decoder: H=1024, B=4096, T=128, IN=1.
// R14 (resubmitted verbatim after infra timeout; never measured).
// R14 = R13 (256x256 tile, 4-phase, double-buffered 128 KiB LDS, XOR swizzle,
// XCD-grouped grid, rank-1 pred fold, bf16 h/c) with the wait discipline
// fixed per m218/m201 (T4 counted-vmcnt):
//  - stage ALL 8 loads for tile t+1 in one burst at phase 0 of tile t
//  - ONE wait per tile: vmcnt(0) at phase 3 (loads are 3 phases old there;
//    drain is cheap). No per-phase vmcnt(2) (R13's 1-phase slack was the
//    regression: every phase serialized on L2/L3/HBM round-trip latency).
//  - certification: tile-(t+1) LDS buffer complete at t@p3's barrier; first
//    read of it at t+1@p0. Stage into the old buffer starts at t@p0, after
//    the last read of it (t-1@p2) has passed t-1@p3's barrier. Race-free.

#define HH 1024
#define BB 4096
#define TT 128

#define BM 256            // batch rows per block
#define BN 256            // weight rows per block = 4 gates x 64 j
#define BKK 64            // K tile
#define NT (HH / BKK)     // 16 K-tiles

typedef __bf16 bf16;
typedef __bf16 v8bf __attribute__((ext_vector_type(8)));
typedef float f32x4 __attribute__((ext_vector_type(4)));

__device__ __forceinline__ float fast_sigmoid(float x) {
    return 1.0f / (1.0f + __expf(-x));
}
__device__ __forceinline__ float fast_tanh(float x) {
    return 1.0f - 2.0f / (__expf(2.0f * x) + 1.0f);
}

__device__ __forceinline__ void gload_lds16(const void* g, void* l) {
    __builtin_amdgcn_global_load_lds(
        (const __attribute__((address_space(1))) uint32_t*)(uintptr_t)g,
        (__attribute__((address_space(3))) uint32_t*)(uint32_t)(uintptr_t)l,
        16, 0, 0);
}

#define FENCE() asm volatile("" ::: "memory")
#define BAR() do { FENCE(); __builtin_amdgcn_s_barrier(); FENCE(); } while (0)
#define WAITV0() asm volatile("s_waitcnt vmcnt(0)" ::: "memory")

// ---- Prologue kernels ------------------------------------------------------

// Wr row layout: nb*256 + g*64 + jj  <->  Whh row g*HH + nb*64 + jj
// Wr0 = pure Whh (for t=0); Wr1 = Whh + Wih (x) Wout (for t>=1).
__global__ void prep_weights(const float* __restrict__ Whh,
                             const float* __restrict__ bih,
                             const float* __restrict__ bhh,
                             const float* __restrict__ Wih,
                             const float* __restrict__ Wout,
                             const float* __restrict__ bout,
                             bf16* __restrict__ Wr0, bf16* __restrict__ Wr1,
                             float* __restrict__ bias0, float* __restrict__ bias1) {
    int idx = blockIdx.x * blockDim.x + threadIdx.x;
    if (idx < 4 * HH * HH) {
        int k   = idx & (HH - 1);
        int row = idx >> 10;
        int nb  = row >> 8;
        int g   = (row >> 6) & 3;
        int jj  = row & 63;
        int srow = g * HH + nb * 64 + jj;
        float wv = Whh[srow * HH + k];
        Wr0[idx] = (bf16)wv;
        Wr1[idx] = (bf16)(wv + Wih[srow] * Wout[k]);
    }
    if (idx < 4 * HH) {
        float b = bih[idx] + bhh[idx];
        bias0[idx] = b;
        bias1[idx] = b + Wih[idx] * bout[0];
    }
}

__global__ void prep_h(const float* __restrict__ h0, bf16* __restrict__ hb) {
    int idx = blockIdx.x * blockDim.x + threadIdx.x;
    if (idx < BB * HH) hb[idx] = (bf16)h0[idx];
}

__global__ void prep_c(const float* __restrict__ c0, bf16* __restrict__ cb) {
    int idx = blockIdx.x * blockDim.x + threadIdx.x;
    if (idx < BB * HH) cb[idx] = (bf16)c0[idx];
}

// all pred slots = b_out; atomics add the raw dot on top
__global__ void prep_pred(float* __restrict__ predbuf, const float* __restrict__ b_out) {
    int idx = blockIdx.x * blockDim.x + threadIdx.x;
    if (idx < (TT + 1) * BB) predbuf[idx] = b_out[0];
}

// ---- Per-step fused GEMM + cell update ------------------------------------
// 256 blocks = 16 nb x 16 mb. Block tile: 256 batch x 256 weight rows.
// Wave (waveM, waveN): 128 batch x (4 gates x 16 j); acc[mi][g].

__global__ __launch_bounds__(512, 2)
void lstm_step(const bf16* __restrict__ hread, bf16* __restrict__ hwrite,
               bf16* __restrict__ cbuf,
               const bf16* __restrict__ Wr, const float* __restrict__ biasp,
               const float* __restrict__ Wout, float* __restrict__ predbuf_w) {
    // unpadded 128-B rows, XOR-swizzled: phys 16B-chunk = logical ^ (row&7)
    __shared__ __align__(16) bf16 As[2][BM][BKK];   // h tiles:  2 x 256 x 64 (64 KB)
    __shared__ __align__(16) bf16 Bs[2][BN][BKK];   // weights:  2 x 256 x 64 (64 KB)

    const int tid   = threadIdx.x;
    const int lane  = tid & 63;
    const int w     = tid >> 6;        // 0..7
    const int waveM = w >> 2;          // 0..1 : batch half
    const int waveN = w & 3;           // 0..3 : j quarter
    const int quad  = lane >> 4, l15 = lane & 15;
    const int swr   = l15 & 7;         // read-side swizzle key (row & 7)

    // bijective XCD swizzle: XCD x owns nb in [(x&3)*4,+4), mb in [(x>>2)*8,+8)
    const int bid = blockIdx.x;
    const int xcd = bid & 7, loc = bid >> 3;
    const int nb  = (xcd & 3) * 4 + (loc & 3);     // 0..15 weight block
    const int mb  = (xcd >> 2) * 8 + (loc >> 2);   // 0..15 batch block
    const int blockB = mb * BM;

    const bf16* Asrc = hread + (size_t)blockB * HH;
    const bf16* Bsrc = Wr + (size_t)nb * BN * HH;

    const int r8  = lane >> 3;              // 0..7 row within 8-row stage group
    const int gc8 = ((lane & 7) ^ r8) * 8;  // pre-swizzled global chunk (elems)

    // epilogue constants; bias folded into acc init
    const int j = nb * 64 + waveN * 16 + l15;
    const float wo = Wout[j];

    f32x4 acc[8][4];  // [m-frag][gate], bias-initialized
#pragma unroll
    for (int g = 0; g < 4; g++) {
        const float bv = biasp[g * HH + j];
#pragma unroll
        for (int mi = 0; mi < 8; mi++)
            acc[mi][g] = (f32x4){bv, bv, bv, bv};
    }

    // ---- prologue: stage K-tile 0 into buffer 0, one-time full drain ----
#pragma unroll
    for (int h2 = 0; h2 < 2; h2++)
#pragma unroll
        for (int c = 0; c < 2; c++) {
            const int rowb = h2 * 128 + w * 16 + c * 8;
            gload_lds16(Asrc + (size_t)(rowb + r8) * HH + gc8, &As[0][rowb][0]);
            gload_lds16(Bsrc + (size_t)(rowb + r8) * HH + gc8, &Bs[0][rowb][0]);
        }
    WAITV0();
    BAR();

    // ---- main loop: 16 K-tiles x 4 phases ----
    for (int t = 0; t < NT; t++) {
        const int buf = t & 1, nxt = buf ^ 1;
        const int kn = (t + 1) * BKK;       // next tile's K offset (elems)
        const bool dost = (t < NT - 1);
        v8bf a[4][2], b[4][2];
#pragma unroll
        for (int p = 0; p < 4; p++) {
            // --- ds_read register subtiles for this phase ---
            if (p == 0 || p == 2) {         // A fragments for qm = p>>1
                const int qm = p >> 1;
#pragma unroll
                for (int mi = 0; mi < 4; mi++)
#pragma unroll
                    for (int kk = 0; kk < 2; kk++)
                        a[mi][kk] = *(const v8bf*)
                            &As[buf][waveM * 128 + qm * 64 + mi * 16 + l15]
                                [((kk * 4 + quad) ^ swr) * 8];
            }
            if (p <= 1) {                   // B fragments: gates 2p, 2p+1
#pragma unroll
                for (int g2 = 0; g2 < 2; g2++)
#pragma unroll
                    for (int kk = 0; kk < 2; kk++)
                        b[p * 2 + g2][kk] = *(const v8bf*)
                            &Bs[buf][(p * 2 + g2) * 64 + waveN * 16 + l15]
                                [((kk * 4 + quad) ^ swr) * 8];
            }
            // --- phase 0: stage ALL of tile t+1 in one burst (8 loads) ---
            if (p == 0 && dost) {
#pragma unroll
                for (int c = 0; c < 4; c++) {
                    const int rowb = w * 32 + c * 8;
                    gload_lds16(Asrc + (size_t)(rowb + r8) * HH + kn + gc8,
                                &As[nxt][rowb][0]);
                }
#pragma unroll
                for (int c = 0; c < 4; c++) {
                    const int rowb = w * 32 + c * 8;
                    gload_lds16(Bsrc + (size_t)(rowb + r8) * HH + kn + gc8,
                                &Bs[nxt][rowb][0]);
                }
            }
            // --- single counted wait per tile: loads are 3 phases old ---
            if (p == 3) WAITV0();
            BAR();
            __builtin_amdgcn_s_setprio(1);
            {
                const int qm = p >> 1, qn = p & 1;
#pragma unroll
                for (int mi = 0; mi < 4; mi++)
#pragma unroll
                    for (int g2 = 0; g2 < 2; g2++)
#pragma unroll
                        for (int kk = 0; kk < 2; kk++)
                            acc[qm * 4 + mi][qn * 2 + g2] =
                                __builtin_amdgcn_mfma_f32_16x16x32_bf16(
                                    a[mi][kk], b[qn * 2 + g2][kk],
                                    acc[qm * 4 + mi][qn * 2 + g2], 0, 0, 0);
            }
            __builtin_amdgcn_s_setprio(0);
            BAR();
        }
    }

    // ---- Epilogue: acc[mi][g][r] = gate g (bias incl.) at (batch, j):
    //   batch = blockB + waveM*128 + mi*16 + quad*4 + r
    //   j     = nb*64 + waveN*16 + l15
#pragma unroll
    for (int mi = 0; mi < 8; mi++) {
#pragma unroll
        for (int r = 0; r < 4; r++) {
            const int bq = blockB + waveM * 128 + mi * 16 + quad * 4 + r;
            const float gi = acc[mi][0][r];
            const float gf = acc[mi][1][r];
            const float gg = acc[mi][2][r];
            const float go = acc[mi][3][r];
            const float cprev = (float)cbuf[(size_t)bq * HH + j];
            const float cn = fast_sigmoid(gf) * cprev
                           + fast_sigmoid(gi) * fast_tanh(gg);
            cbuf[(size_t)bq * HH + j] = (bf16)cn;   // in-place, 1 owner/elem
            const float hn = fast_sigmoid(go) * fast_tanh(cn);
            hwrite[(size_t)bq * HH + j] = (bf16)hn;
            float pacc = hn * wo;
            pacc += __shfl_xor(pacc, 1);
            pacc += __shfl_xor(pacc, 2);
            pacc += __shfl_xor(pacc, 4);
            pacc += __shfl_xor(pacc, 8);
            if (l15 == 0) atomicAdd(&predbuf_w[bq], pacc);
        }
    }
}

// ---- Output transpose: out[b][t] = pred_t[b] ------------------------------

__global__ void write_out(const float* __restrict__ predbuf, float* __restrict__ out) {
    int idx = blockIdx.x * blockDim.x + threadIdx.x;
    if (idx < BB * TT) {
        int t = idx & (TT - 1);
        int b = idx >> 7;
        out[idx] = predbuf[(size_t)(t + 1) * BB + b];
    }
}

// ---- Host launch -----------------------------------------------------------

extern "C" void kernel_launch(void* const* d_in, const int* in_sizes, int n_in,
                              void* d_out, int out_size, void* d_ws, size_t ws_size,
                              hipStream_t stream) {
    const float* hidden = (const float*)d_in[0];
    const float* cell   = (const float*)d_in[1];
    const float* Wih    = (const float*)d_in[2];
    const float* Whh    = (const float*)d_in[3];
    const float* bih    = (const float*)d_in[4];
    const float* bhh    = (const float*)d_in[5];
    const float* Wout   = (const float*)d_in[6];
    const float* bout   = (const float*)d_in[7];
    float* out = (float*)d_out;

    char* ws = (char*)d_ws;
    bf16* Wr0 = (bf16*)ws;       ws += (size_t)4 * HH * HH * 2;   // 8 MB
    bf16* Wr1 = (bf16*)ws;       ws += (size_t)4 * HH * HH * 2;   // 8 MB
    bf16* hb0 = (bf16*)ws;       ws += (size_t)BB * HH * 2;       // 8 MB
    bf16* hb1 = (bf16*)ws;       ws += (size_t)BB * HH * 2;       // 8 MB
    bf16* cbuf = (bf16*)ws;      ws += (size_t)BB * HH * 2;       // 8 MB
    float* bias0 = (float*)ws;   ws += (size_t)4 * HH * 4;        // 16 KB
    float* bias1 = (float*)ws;   ws += (size_t)4 * HH * 4;        // 16 KB
    float* predbuf = (float*)ws; ws += (size_t)(TT + 1) * BB * 4; // 2.1 MB

    prep_weights<<<(4 * HH * HH + 255) / 256, 256, 0, stream>>>(
        Whh, bih, bhh, Wih, Wout, bout, Wr0, Wr1, bias0, bias1);
    prep_h<<<(BB * HH + 255) / 256, 256, 0, stream>>>(hidden, hb0);
    prep_c<<<(BB * HH + 255) / 256, 256, 0, stream>>>(cell, cbuf);
    prep_pred<<<((TT + 1) * BB + 255) / 256, 256, 0, stream>>>(predbuf, bout);

    bf16* hb[2] = {hb0, hb1};
    for (int t = 0; t < TT; t++) {
        const bf16* hr = hb[t & 1];
        bf16* hw = hb[(t + 1) & 1];
        const bf16* Wr   = (t == 0) ? Wr0 : Wr1;
        const float* bsp = (t == 0) ? bias0 : bias1;
        lstm_step<<<256, 512, 0, stream>>>(
            hr, hw, cbuf, Wr, bsp, Wout, predbuf + (size_t)(t + 1) * BB);
    }

    write_out<<<(BB * TT + 255) / 256, 256, 0, stream>>>(predbuf, out);
}

// Round 5
// 6462.428 us; speedup vs baseline: 1.0921x; 1.0921x over previous
//
#include <hip/hip_runtime.h>
#include <hip/hip_bf16.h>
#include <stdint.h>

// LSTM decoder: H=1024, B=4096, T=128, IN=1.
// R16 = R15 with the macro-hygiene compile fix (BUF threaded through
// READ_A/READ_B as an explicit parameter). Semantics identical to R15:
// R14 geometry (256x256 tile, BK=64, dbuf 128 KiB LDS, XOR swizzle,
// XCD-grouped grid, rank-1 pred fold, bf16 h/c) with sync collapsed from
// 8 barriers/tile to ONE barrier/tile:
//  - R13 (per-phase vmcnt(2)) == R14 (burst + vmcnt(0)@p3) at ~58 us proved
//    staging waits are NOT the stall; the per-phase BAR pairs were exposing
//    full ds_read port+latency serially before each 16-MFMA cluster
//    (model ~8.5K cyc/tile == measured 8850; floor ~2800).
//  - within a K-tile all reads target the same certified buffer -> no
//    inter-phase barriers needed. Tile body is straight-line: reads(p0) ->
//    8 gloads(buf^1) -> MFMA(p0) -> reads(p1) -> MFMA(p1) -> reads(p2) ->
//    MFMA(p2) -> MFMA(p3) -> lgkmcnt(0) (free) -> vmcnt(0) (free, 1 tile
//    old) -> BAR. Compiler free to pipeline reads under MFMA (partial
//    lgkmcnt), gloads under everything (vmcnt).
//  - hazards: gloads->buf^1 issue after entry BAR which followed lgkmcnt(0)
//    of prior tile's buf^1 reads; reads of buf precede the BAR preceding
//    writes of buf. 2x-unrolled loop for compile-time buf index.

#define HH 1024
#define BB 4096
#define TT 128

#define BM 256            // batch rows per block
#define BN 256            // weight rows per block = 4 gates x 64 j
#define BKK 64            // K tile
#define NT (HH / BKK)     // 16 K-tiles

typedef __bf16 bf16;
typedef __bf16 v8bf __attribute__((ext_vector_type(8)));
typedef float f32x4 __attribute__((ext_vector_type(4)));

__device__ __forceinline__ float fast_sigmoid(float x) {
    return 1.0f / (1.0f + __expf(-x));
}
__device__ __forceinline__ float fast_tanh(float x) {
    return 1.0f - 2.0f / (__expf(2.0f * x) + 1.0f);
}

__device__ __forceinline__ void gload_lds16(const void* g, void* l) {
    __builtin_amdgcn_global_load_lds(
        (const __attribute__((address_space(1))) uint32_t*)(uintptr_t)g,
        (__attribute__((address_space(3))) uint32_t*)(uint32_t)(uintptr_t)l,
        16, 0, 0);
}

#define FENCE() asm volatile("" ::: "memory")
#define BAR() do { FENCE(); __builtin_amdgcn_s_barrier(); FENCE(); } while (0)
#define WAITV0() asm volatile("s_waitcnt vmcnt(0)" ::: "memory")
#define WAITL0() asm volatile("s_waitcnt lgkmcnt(0)" ::: "memory")

// ---- Prologue kernels ------------------------------------------------------

// Wr row layout: nb*256 + g*64 + jj  <->  Whh row g*HH + nb*64 + jj
// Wr0 = pure Whh (for t=0); Wr1 = Whh + Wih (x) Wout (for t>=1).
__global__ void prep_weights(const float* __restrict__ Whh,
                             const float* __restrict__ bih,
                             const float* __restrict__ bhh,
                             const float* __restrict__ Wih,
                             const float* __restrict__ Wout,
                             const float* __restrict__ bout,
                             bf16* __restrict__ Wr0, bf16* __restrict__ Wr1,
                             float* __restrict__ bias0, float* __restrict__ bias1) {
    int idx = blockIdx.x * blockDim.x + threadIdx.x;
    if (idx < 4 * HH * HH) {
        int k   = idx & (HH - 1);
        int row = idx >> 10;
        int nb  = row >> 8;
        int g   = (row >> 6) & 3;
        int jj  = row & 63;
        int srow = g * HH + nb * 64 + jj;
        float wv = Whh[srow * HH + k];
        Wr0[idx] = (bf16)wv;
        Wr1[idx] = (bf16)(wv + Wih[srow] * Wout[k]);
    }
    if (idx < 4 * HH) {
        float b = bih[idx] + bhh[idx];
        bias0[idx] = b;
        bias1[idx] = b + Wih[idx] * bout[0];
    }
}

__global__ void prep_h(const float* __restrict__ h0, bf16* __restrict__ hb) {
    int idx = blockIdx.x * blockDim.x + threadIdx.x;
    if (idx < BB * HH) hb[idx] = (bf16)h0[idx];
}

__global__ void prep_c(const float* __restrict__ c0, bf16* __restrict__ cb) {
    int idx = blockIdx.x * blockDim.x + threadIdx.x;
    if (idx < BB * HH) cb[idx] = (bf16)c0[idx];
}

// all pred slots = b_out; atomics add the raw dot on top
__global__ void prep_pred(float* __restrict__ predbuf, const float* __restrict__ b_out) {
    int idx = blockIdx.x * blockDim.x + threadIdx.x;
    if (idx < (TT + 1) * BB) predbuf[idx] = b_out[0];
}

// ---- Per-step fused GEMM + cell update ------------------------------------
// 256 blocks = 16 nb x 16 mb. Block tile: 256 batch x 256 weight rows.
// Wave (waveM, waveN): 128 batch x (4 gates x 16 j); acc[mi][g].

// Tile body: BUF threaded explicitly so it reaches inner macros as a literal.
#define READ_A(BUF, dst, QM)                                                   \
    _Pragma("unroll")                                                          \
    for (int mi = 0; mi < 4; mi++)                                             \
        _Pragma("unroll")                                                      \
        for (int kk = 0; kk < 2; kk++)                                         \
            dst[mi][kk] = *(const v8bf*)                                       \
                &As[BUF][waveM * 128 + (QM) * 64 + mi * 16 + l15]              \
                    [((kk * 4 + quad) ^ swr) * 8];

#define READ_B(BUF, G0)                                                        \
    _Pragma("unroll")                                                          \
    for (int g2 = 0; g2 < 2; g2++)                                             \
        _Pragma("unroll")                                                      \
        for (int kk = 0; kk < 2; kk++)                                         \
            bb[(G0) + g2][kk] = *(const v8bf*)                                 \
                &Bs[BUF][((G0) + g2) * 64 + waveN * 16 + l15]                  \
                    [((kk * 4 + quad) ^ swr) * 8];

#define MFMA_Q(asrcv, QM, QN)                                                  \
    __builtin_amdgcn_s_setprio(1);                                             \
    _Pragma("unroll")                                                          \
    for (int mi = 0; mi < 4; mi++)                                             \
        _Pragma("unroll")                                                      \
        for (int g2 = 0; g2 < 2; g2++)                                         \
            _Pragma("unroll")                                                  \
            for (int kk = 0; kk < 2; kk++)                                     \
                acc[(QM) * 4 + mi][(QN) * 2 + g2] =                            \
                    __builtin_amdgcn_mfma_f32_16x16x32_bf16(                   \
                        asrcv[mi][kk], bb[(QN) * 2 + g2][kk],                  \
                        acc[(QM) * 4 + mi][(QN) * 2 + g2], 0, 0, 0);           \
    __builtin_amdgcn_s_setprio(0);

#define TILE_BODY(BUF, TIDX)                                                   \
    {                                                                          \
        const int t_ = (TIDX);                                                 \
        const bool dost_ = (t_ < NT - 1);                                      \
        const int kn_ = (t_ + 1) * BKK;                                        \
        v8bf a0[4][2], a1[4][2], bb[4][2];                                     \
        READ_A(BUF, a0, 0)                                                     \
        READ_B(BUF, 0)                                                         \
        if (dost_) {                                                           \
            _Pragma("unroll")                                                  \
            for (int c = 0; c < 4; c++) {                                      \
                const int rowb = w * 32 + c * 8;                               \
                gload_lds16(Asrc + (size_t)(rowb + r8) * HH + kn_ + gc8,       \
                            &As[1 - (BUF)][rowb][0]);                          \
            }                                                                  \
            _Pragma("unroll")                                                  \
            for (int c = 0; c < 4; c++) {                                      \
                const int rowb = w * 32 + c * 8;                               \
                gload_lds16(Bsrc + (size_t)(rowb + r8) * HH + kn_ + gc8,       \
                            &Bs[1 - (BUF)][rowb][0]);                          \
            }                                                                  \
        }                                                                      \
        MFMA_Q(a0, 0, 0)                                                       \
        READ_B(BUF, 2)                                                         \
        MFMA_Q(a0, 0, 1)                                                       \
        READ_A(BUF, a1, 1)                                                     \
        MFMA_Q(a1, 1, 0)                                                       \
        MFMA_Q(a1, 1, 1)                                                       \
        WAITL0();                                                              \
        WAITV0();                                                              \
        BAR();                                                                 \
    }

__global__ __launch_bounds__(512, 2)
void lstm_step(const bf16* __restrict__ hread, bf16* __restrict__ hwrite,
               bf16* __restrict__ cbuf,
               const bf16* __restrict__ Wr, const float* __restrict__ biasp,
               const float* __restrict__ Wout, float* __restrict__ predbuf_w) {
    // unpadded 128-B rows, XOR-swizzled: phys 16B-chunk = logical ^ (row&7)
    __shared__ __align__(16) bf16 As[2][BM][BKK];   // h tiles:  2 x 256 x 64 (64 KB)
    __shared__ __align__(16) bf16 Bs[2][BN][BKK];   // weights:  2 x 256 x 64 (64 KB)

    const int tid   = threadIdx.x;
    const int lane  = tid & 63;
    const int w     = tid >> 6;        // 0..7
    const int waveM = w >> 2;          // 0..1 : batch half
    const int waveN = w & 3;           // 0..3 : j quarter
    const int quad  = lane >> 4, l15 = lane & 15;
    const int swr   = l15 & 7;         // read-side swizzle key (row & 7)

    // bijective XCD swizzle: XCD x owns nb in [(x&3)*4,+4), mb in [(x>>2)*8,+8)
    const int bid = blockIdx.x;
    const int xcd = bid & 7, loc = bid >> 3;
    const int nb  = (xcd & 3) * 4 + (loc & 3);     // 0..15 weight block
    const int mb  = (xcd >> 2) * 8 + (loc >> 2);   // 0..15 batch block
    const int blockB = mb * BM;

    const bf16* Asrc = hread + (size_t)blockB * HH;
    const bf16* Bsrc = Wr + (size_t)nb * BN * HH;

    const int r8  = lane >> 3;              // 0..7 row within 8-row stage group
    const int gc8 = ((lane & 7) ^ r8) * 8;  // pre-swizzled global chunk (elems)

    // epilogue constants; bias folded into acc init
    const int j = nb * 64 + waveN * 16 + l15;
    const float wo = Wout[j];

    f32x4 acc[8][4];  // [m-frag][gate], bias-initialized
#pragma unroll
    for (int g = 0; g < 4; g++) {
        const float bv = biasp[g * HH + j];
#pragma unroll
        for (int mi = 0; mi < 8; mi++)
            acc[mi][g] = (f32x4){bv, bv, bv, bv};
    }

    // ---- prologue: stage K-tile 0 into buffer 0, one-time full drain ----
#pragma unroll
    for (int h2 = 0; h2 < 2; h2++)
#pragma unroll
        for (int c = 0; c < 2; c++) {
            const int rowb = h2 * 128 + w * 16 + c * 8;
            gload_lds16(Asrc + (size_t)(rowb + r8) * HH + gc8, &As[0][rowb][0]);
            gload_lds16(Bsrc + (size_t)(rowb + r8) * HH + gc8, &Bs[0][rowb][0]);
        }
    WAITV0();
    BAR();

    // ---- main loop: 16 K-tiles, 2x unrolled for compile-time buf ----
#pragma unroll 1
    for (int tt = 0; tt < NT / 2; tt++) {
        TILE_BODY(0, 2 * tt)
        TILE_BODY(1, 2 * tt + 1)
    }

    // ---- Epilogue: acc[mi][g][r] = gate g (bias incl.) at (batch, j):
    //   batch = blockB + waveM*128 + mi*16 + quad*4 + r
    //   j     = nb*64 + waveN*16 + l15
#pragma unroll
    for (int mi = 0; mi < 8; mi++) {
#pragma unroll
        for (int r = 0; r < 4; r++) {
            const int bq = blockB + waveM * 128 + mi * 16 + quad * 4 + r;
            const float gi = acc[mi][0][r];
            const float gf = acc[mi][1][r];
            const float gg = acc[mi][2][r];
            const float go = acc[mi][3][r];
            const float cprev = (float)cbuf[(size_t)bq * HH + j];
            const float cn = fast_sigmoid(gf) * cprev
                           + fast_sigmoid(gi) * fast_tanh(gg);
            cbuf[(size_t)bq * HH + j] = (bf16)cn;   // in-place, 1 owner/elem
            const float hn = fast_sigmoid(go) * fast_tanh(cn);
            hwrite[(size_t)bq * HH + j] = (bf16)hn;
            float pacc = hn * wo;
            pacc += __shfl_xor(pacc, 1);
            pacc += __shfl_xor(pacc, 2);
            pacc += __shfl_xor(pacc, 4);
            pacc += __shfl_xor(pacc, 8);
            if (l15 == 0) atomicAdd(&predbuf_w[bq], pacc);
        }
    }
}

// ---- Output transpose: out[b][t] = pred_t[b] ------------------------------

__global__ void write_out(const float* __restrict__ predbuf, float* __restrict__ out) {
    int idx = blockIdx.x * blockDim.x + threadIdx.x;
    if (idx < BB * TT) {
        int t = idx & (TT - 1);
        int b = idx >> 7;
        out[idx] = predbuf[(size_t)(t + 1) * BB + b];
    }
}

// ---- Host launch -----------------------------------------------------------

extern "C" void kernel_launch(void* const* d_in, const int* in_sizes, int n_in,
                              void* d_out, int out_size, void* d_ws, size_t ws_size,
                              hipStream_t stream) {
    const float* hidden = (const float*)d_in[0];
    const float* cell   = (const float*)d_in[1];
    const float* Wih    = (const float*)d_in[2];
    const float* Whh    = (const float*)d_in[3];
    const float* bih    = (const float*)d_in[4];
    const float* bhh    = (const float*)d_in[5];
    const float* Wout   = (const float*)d_in[6];
    const float* bout   = (const float*)d_in[7];
    float* out = (float*)d_out;

    char* ws = (char*)d_ws;
    bf16* Wr0 = (bf16*)ws;       ws += (size_t)4 * HH * HH * 2;   // 8 MB
    bf16* Wr1 = (bf16*)ws;       ws += (size_t)4 * HH * HH * 2;   // 8 MB
    bf16* hb0 = (bf16*)ws;       ws += (size_t)BB * HH * 2;       // 8 MB
    bf16* hb1 = (bf16*)ws;       ws += (size_t)BB * HH * 2;       // 8 MB
    bf16* cbuf = (bf16*)ws;      ws += (size_t)BB * HH * 2;       // 8 MB
    float* bias0 = (float*)ws;   ws += (size_t)4 * HH * 4;        // 16 KB
    float* bias1 = (float*)ws;   ws += (size_t)4 * HH * 4;        // 16 KB
    float* predbuf = (float*)ws; ws += (size_t)(TT + 1) * BB * 4; // 2.1 MB

    prep_weights<<<(4 * HH * HH + 255) / 256, 256, 0, stream>>>(
        Whh, bih, bhh, Wih, Wout, bout, Wr0, Wr1, bias0, bias1);
    prep_h<<<(BB * HH + 255) / 256, 256, 0, stream>>>(hidden, hb0);
    prep_c<<<(BB * HH + 255) / 256, 256, 0, stream>>>(cell, cbuf);
    prep_pred<<<((TT + 1) * BB + 255) / 256, 256, 0, stream>>>(predbuf, bout);

    bf16* hb[2] = {hb0, hb1};
    for (int t = 0; t < TT; t++) {
        const bf16* hr = hb[t & 1];
        bf16* hw = hb[(t + 1) & 1];
        const bf16* Wr   = (t == 0) ? Wr0 : Wr1;
        const float* bsp = (t == 0) ? bias0 : bias1;
        lstm_step<<<256, 512, 0, stream>>>(
            hr, hw, cbuf, Wr, bsp, Wout, predbuf + (size_t)(t + 1) * BB);
    }

    write_out<<<(BB * TT + 255) / 256, 256, 0, stream>>>(predbuf, out);
}

// Round 7
// 5744.953 us; speedup vs baseline: 1.2284x; 1.1249x over previous
//
#include <hip/hip_runtime.h>
#include <hip/hip_bf16.h>
#include <stdint.h>

// LSTM decoder: H=1024, B=4096, T=128, IN=1.
// R18 = R17 resubmitted verbatim after container-level infra failure (never
// compiled/measured). R17: back to R12's proven geometry (BM=128 x BN=256,
// 256 thr / 4 waves, grid 512 -> 2 blocks/CU for cross-block TLP) + BK=32
// TRIPLE-buffered LDS (72 KiB, still 2 blocks/CU) so the in-loop wait is
// vmcnt(6), never 0:
//  - R13/R14/R16 (256^2, 128 KiB, 1 block/CU) all ~55-59 us regardless of
//    sync structure; R12 (2 blocks/CU) was 41.7 -> occupancy is the lever.
//  - per-tile vmcnt(0) is the m97 ~880TF mechanism; 3-deep prefetch gives
//    tile t's stage (for t+2) a full tile of slack; end-of-tile waits only
//    for loads issued at t-1 (vmcnt(6) = this tile's 6 stay in flight).
//  - packed LDS rows: two 64-B K32 rows per 128-B LDS row, XOR key
//    (ldsrow&7) -> 2-way-max bank pattern; fragment reads are lane-constant
//    address + compile-time offset. Layout identity verified:
//    p=(c+4*(br&1))^((br>>1)&7) with staging lane l -> p=l&7 when base%8==0.
//  - numerics/epilogue/prep identical to R12 (rank-1 pred fold, bf16 h/c,
//    same MFMA k-order -> same rounding).

#define HH 1024
#define BB 4096
#define TT 128

#define BM 128            // batch rows per block
#define BN 256            // weight rows per block = 4 gates x 64 j
#define BKK 32            // K tile
#define NTIL 32           // K tiles (HH/BKK)

typedef __bf16 bf16;
typedef __bf16 v8bf __attribute__((ext_vector_type(8)));
typedef float f32x4 __attribute__((ext_vector_type(4)));

__device__ __forceinline__ float fast_sigmoid(float x) {
    return 1.0f / (1.0f + __expf(-x));
}
__device__ __forceinline__ float fast_tanh(float x) {
    return 1.0f - 2.0f / (__expf(2.0f * x) + 1.0f);
}

__device__ __forceinline__ void gload_lds16(const void* g, void* l) {
    __builtin_amdgcn_global_load_lds(
        (const __attribute__((address_space(1))) uint32_t*)(uintptr_t)g,
        (__attribute__((address_space(3))) uint32_t*)(uint32_t)(uintptr_t)l,
        16, 0, 0);
}

#define FENCE() asm volatile("" ::: "memory")
#define BAR() do { FENCE(); __builtin_amdgcn_s_barrier(); FENCE(); } while (0)
#define WAITV0() asm volatile("s_waitcnt vmcnt(0)" ::: "memory")
#define WAITV6() asm volatile("s_waitcnt vmcnt(6)" ::: "memory")
#define WAITL0() asm volatile("s_waitcnt lgkmcnt(0)" ::: "memory")

// ---- Prologue kernels ------------------------------------------------------

// Wr row layout: jb2*256 + g*64 + jj  <->  Whh row g*HH + jb2*64 + jj
// Wr0 = pure Whh (for t=0); Wr1 = Whh + Wih (x) Wout (for t>=1).
__global__ void prep_weights(const float* __restrict__ Whh,
                             const float* __restrict__ bih,
                             const float* __restrict__ bhh,
                             const float* __restrict__ Wih,
                             const float* __restrict__ Wout,
                             const float* __restrict__ bout,
                             bf16* __restrict__ Wr0, bf16* __restrict__ Wr1,
                             float* __restrict__ bias0, float* __restrict__ bias1) {
    int idx = blockIdx.x * blockDim.x + threadIdx.x;
    if (idx < 4 * HH * HH) {
        int k   = idx & (HH - 1);
        int row = idx >> 10;
        int jb2 = row >> 8;
        int g   = (row >> 6) & 3;
        int jj  = row & 63;
        int srow = g * HH + jb2 * 64 + jj;
        float wv = Whh[srow * HH + k];
        Wr0[idx] = (bf16)wv;
        Wr1[idx] = (bf16)(wv + Wih[srow] * Wout[k]);
    }
    if (idx < 4 * HH) {
        float b = bih[idx] + bhh[idx];
        bias0[idx] = b;
        bias1[idx] = b + Wih[idx] * bout[0];
    }
}

__global__ void prep_h(const float* __restrict__ h0, bf16* __restrict__ hb) {
    int idx = blockIdx.x * blockDim.x + threadIdx.x;
    if (idx < BB * HH) hb[idx] = (bf16)h0[idx];
}

__global__ void prep_c(const float* __restrict__ c0, bf16* __restrict__ cb) {
    int idx = blockIdx.x * blockDim.x + threadIdx.x;
    if (idx < BB * HH) cb[idx] = (bf16)c0[idx];
}

// all pred slots = b_out; atomics add the raw dot on top
__global__ void prep_pred(float* __restrict__ predbuf, const float* __restrict__ b_out) {
    int idx = blockIdx.x * blockDim.x + threadIdx.x;
    if (idx < (TT + 1) * BB) predbuf[idx] = b_out[0];
}

// ---- Per-step fused GEMM + cell update ------------------------------------
// 512 blocks = 16 jb2 x 32 mb. Block tile: 128 batch x 256 weight rows.
// Wave (waveM, waveN): 64 batch x 128 wrows; acc[mi][g*2+jh].
// LDS: packed rows — LDS-row R (128 B) holds K32-rows 2R (first 64 B) and
// 2R+1; logical (row br, chunk c in 0..3) lives at LDS-row br>>1, phys chunk
// p = (c + 4*(br&1)) ^ ((br>>1)&7).

// Stage one 1-KB call: 8 LDS-rows (16 global rows) from Src at k-offset KN.
// Per-lane source: t1=(l&7)^(l>>3) -> s=t1>>2, c=t1&3, grow=2*(l>>3)+s.
// SrcL = Src + grow*HH + c*8 precomputed per lane.
#define STAGE1(SrcL, dstArr, TGT, ldsRowBase, KN)                              \
    gload_lds16((SrcL) + (size_t)(2 * (ldsRowBase)) * HH + (KN),               \
                &dstArr[TGT][ldsRowBase][0]);

#define READ_FRAGS(BUF)                                                        \
    _Pragma("unroll")                                                          \
    for (int mi = 0; mi < 4; mi++)                                             \
        a[mi] = *(const v8bf*)&As[BUF][waveM * 32 + mi * 8 + rh][pA];          \
    _Pragma("unroll")                                                          \
    for (int g = 0; g < 4; g++)                                                \
        _Pragma("unroll")                                                      \
        for (int jh = 0; jh < 2; jh++)                                         \
            b[g * 2 + jh] = *(const v8bf*)                                     \
                &Bs[BUF][g * 32 + waveN * 16 + jh * 8 + rh][pA];

#define MFMA_ALL()                                                             \
    __builtin_amdgcn_s_setprio(1);                                             \
    _Pragma("unroll")                                                          \
    for (int mi = 0; mi < 4; mi++)                                             \
        _Pragma("unroll")                                                      \
        for (int nt = 0; nt < 8; nt++)                                         \
            acc[mi][nt] = __builtin_amdgcn_mfma_f32_16x16x32_bf16(             \
                a[mi], b[nt], acc[mi][nt], 0, 0, 0);                           \
    __builtin_amdgcn_s_setprio(0);

// Tile T: read buf T%3, stage tile T+2 into (T+2)%3, wait vmcnt(6) (in-loop).
#define TILE_BODY(BUF, TGT, T)                                                 \
    {                                                                          \
        v8bf a[4], b[8];                                                       \
        if ((T) < NTIL - 2) {                                                  \
            const int kn_ = ((T) + 2) * BKK;                                   \
            _Pragma("unroll")                                                  \
            for (int c2 = 0; c2 < 2; c2++)                                     \
                STAGE1(AsrcL, As, TGT, w * 16 + c2 * 8, kn_)                   \
            _Pragma("unroll")                                                  \
            for (int c2 = 0; c2 < 4; c2++)                                     \
                STAGE1(BsrcL, Bs, TGT, w * 32 + c2 * 8, kn_)                   \
        }                                                                      \
        READ_FRAGS(BUF)                                                        \
        MFMA_ALL()                                                             \
        WAITL0();                                                              \
        if ((T) < NTIL - 2) { WAITV6(); } else { WAITV0(); }                   \
        BAR();                                                                 \
    }

__global__ __launch_bounds__(256, 2)
void lstm_step(const bf16* __restrict__ hread, bf16* __restrict__ hwrite,
               bf16* __restrict__ cbuf,
               const bf16* __restrict__ Wr, const float* __restrict__ biasp,
               const float* __restrict__ Wout, float* __restrict__ predbuf_w) {
    __shared__ __align__(16) bf16 As[3][64][64];    // h: 3 buf x 64 LDS-rows   (24 KB)
    __shared__ __align__(16) bf16 Bs[3][128][64];   // w: 3 buf x 128 LDS-rows  (48 KB)

    const int tid   = threadIdx.x;
    const int lane  = tid & 63;
    const int w     = tid >> 6;        // 0..3
    const int waveM = w >> 1, waveN = w & 1;
    const int quad  = lane >> 4, l15 = lane & 15;

    const int bid    = blockIdx.x;
    const int jb2    = (bid & 7) * 2 + ((bid >> 3) & 1); // 0..15, XCD-grouped
    const int blockB = (bid >> 4) * BM;                  // batch base

    const bf16* Asrc = hread + (size_t)blockB * HH;
    const bf16* Bsrc = Wr + (size_t)jb2 * 256 * HH;

    // staging per-lane constants: t1=(l&7)^(l>>3); s=t1>>2; c=t1&3
    const int t1  = (lane & 7) ^ (lane >> 3);
    const int grl = 2 * (lane >> 3) + (t1 >> 2);  // global-row offset in 16-row group
    const int c8  = (t1 & 3) * 8;                 // source elem offset
    const bf16* AsrcL = Asrc + (size_t)grl * HH + c8;
    const bf16* BsrcL = Bsrc + (size_t)grl * HH + c8;

    // read-side per-lane constants
    const int rh = l15 >> 1;                       // LDS-row offset
    const int pA = (((quad + 4 * (l15 & 1)) ^ rh)) * 8;  // phys chunk * 8 elems

    // epilogue constants; bias folded into acc init
    float bsvv[2][4], wov[2];
#pragma unroll
    for (int jh = 0; jh < 2; jh++) {
        const int j = jb2 * 64 + waveN * 32 + jh * 16 + l15;
#pragma unroll
        for (int g = 0; g < 4; g++) bsvv[jh][g] = biasp[g * HH + j];
        wov[jh] = Wout[j];
    }

    f32x4 acc[4][8]; // [m-tile][gate*2 + j-half], bias-initialized
#pragma unroll
    for (int mi = 0; mi < 4; mi++)
#pragma unroll
        for (int g = 0; g < 4; g++)
#pragma unroll
            for (int jh = 0; jh < 2; jh++) {
                const float bv = bsvv[jh][g];
                acc[mi][g * 2 + jh] = (f32x4){bv, bv, bv, bv};
            }

    // ---- prologue: stage tiles 0,1 into bufs 0,1; wait tile0 (vmcnt 6) ----
#pragma unroll
    for (int c2 = 0; c2 < 2; c2++) STAGE1(AsrcL, As, 0, w * 16 + c2 * 8, 0)
#pragma unroll
    for (int c2 = 0; c2 < 4; c2++) STAGE1(BsrcL, Bs, 0, w * 32 + c2 * 8, 0)
#pragma unroll
    for (int c2 = 0; c2 < 2; c2++) STAGE1(AsrcL, As, 1, w * 16 + c2 * 8, BKK)
#pragma unroll
    for (int c2 = 0; c2 < 4; c2++) STAGE1(BsrcL, Bs, 1, w * 32 + c2 * 8, BKK)
    WAITV6();
    BAR();

    // ---- main loop: 32 K-tiles, 3x unrolled for compile-time buf ----
#pragma unroll 1
    for (int tt = 0; tt < 10; tt++) {
        TILE_BODY(0, 2, 3 * tt)
        TILE_BODY(1, 0, 3 * tt + 1)
        TILE_BODY(2, 1, 3 * tt + 2)
    }
    TILE_BODY(0, 2, 30)
    TILE_BODY(1, 0, 31)

    // ---- Epilogue: acc[mi][g*2+jh][r] = gate g (bias incl.) at (batch, j):
    //   batch = blockB + waveM*64 + mi*16 + quad*4 + r
    //   j     = jb2*64 + waveN*32 + jh*16 + l15
#pragma unroll
    for (int mi = 0; mi < 4; mi++) {
#pragma unroll
        for (int r = 0; r < 4; r++) {
            const int b = blockB + waveM * 64 + mi * 16 + quad * 4 + r;
            float pacc = 0.0f;
#pragma unroll
            for (int jh = 0; jh < 2; jh++) {
                const int j = jb2 * 64 + waveN * 32 + jh * 16 + l15;
                const float gi = acc[mi][0 + jh][r];
                const float gf = acc[mi][2 + jh][r];
                const float gg = acc[mi][4 + jh][r];
                const float go = acc[mi][6 + jh][r];
                const float cprev = (float)cbuf[(size_t)b * HH + j];
                const float cn = fast_sigmoid(gf) * cprev
                               + fast_sigmoid(gi) * fast_tanh(gg);
                cbuf[(size_t)b * HH + j] = (bf16)cn;   // in-place, 1 owner/elem
                const float hn = fast_sigmoid(go) * fast_tanh(cn);
                hwrite[(size_t)b * HH + j] = (bf16)hn;
                pacc += hn * wov[jh];
            }
            pacc += __shfl_xor(pacc, 1);
            pacc += __shfl_xor(pacc, 2);
            pacc += __shfl_xor(pacc, 4);
            pacc += __shfl_xor(pacc, 8);
            if (l15 == 0) atomicAdd(&predbuf_w[b], pacc);
        }
    }
}

// ---- Output transpose: out[b][t] = pred_t[b] ------------------------------

__global__ void write_out(const float* __restrict__ predbuf, float* __restrict__ out) {
    int idx = blockIdx.x * blockDim.x + threadIdx.x;
    if (idx < BB * TT) {
        int t = idx & (TT - 1);
        int b = idx >> 7;
        out[idx] = predbuf[(size_t)(t + 1) * BB + b];
    }
}

// ---- Host launch -----------------------------------------------------------

extern "C" void kernel_launch(void* const* d_in, const int* in_sizes, int n_in,
                              void* d_out, int out_size, void* d_ws, size_t ws_size,
                              hipStream_t stream) {
    const float* hidden = (const float*)d_in[0];
    const float* cell   = (const float*)d_in[1];
    const float* Wih    = (const float*)d_in[2];
    const float* Whh    = (const float*)d_in[3];
    const float* bih    = (const float*)d_in[4];
    const float* bhh    = (const float*)d_in[5];
    const float* Wout   = (const float*)d_in[6];
    const float* bout   = (const float*)d_in[7];
    float* out = (float*)d_out;

    char* ws = (char*)d_ws;
    bf16* Wr0 = (bf16*)ws;       ws += (size_t)4 * HH * HH * 2;   // 8 MB
    bf16* Wr1 = (bf16*)ws;       ws += (size_t)4 * HH * HH * 2;   // 8 MB
    bf16* hb0 = (bf16*)ws;       ws += (size_t)BB * HH * 2;       // 8 MB
    bf16* hb1 = (bf16*)ws;       ws += (size_t)BB * HH * 2;       // 8 MB
    bf16* cbuf = (bf16*)ws;      ws += (size_t)BB * HH * 2;       // 8 MB
    float* bias0 = (float*)ws;   ws += (size_t)4 * HH * 4;        // 16 KB
    float* bias1 = (float*)ws;   ws += (size_t)4 * HH * 4;        // 16 KB
    float* predbuf = (float*)ws; ws += (size_t)(TT + 1) * BB * 4; // 2.1 MB

    prep_weights<<<(4 * HH * HH + 255) / 256, 256, 0, stream>>>(
        Whh, bih, bhh, Wih, Wout, bout, Wr0, Wr1, bias0, bias1);
    prep_h<<<(BB * HH + 255) / 256, 256, 0, stream>>>(hidden, hb0);
    prep_c<<<(BB * HH + 255) / 256, 256, 0, stream>>>(cell, cbuf);
    prep_pred<<<((TT + 1) * BB + 255) / 256, 256, 0, stream>>>(predbuf, bout);

    bf16* hb[2] = {hb0, hb1};
    for (int t = 0; t < TT; t++) {
        const bf16* hr = hb[t & 1];
        bf16* hw = hb[(t + 1) & 1];
        const bf16* Wr   = (t == 0) ? Wr0 : Wr1;
        const float* bsp = (t == 0) ? bias0 : bias1;
        lstm_step<<<512, 256, 0, stream>>>(
            hr, hw, cbuf, Wr, bsp, Wout, predbuf + (size_t)(t + 1) * BB);
    }

    write_out<<<(BB * TT + 255) / 256, 256, 0, stream>>>(predbuf, out);
}

// Round 8
// 5164.051 us; speedup vs baseline: 1.3666x; 1.1125x over previous
//
#include <hip/hip_runtime.h>
#include <hip/hip_bf16.h>
#include <stdint.h>

// LSTM decoder: H=1024, B=4096, T=128, IN=1.
// R19 = R12 (the measured 41.7us/step champion: BM=128 x BN=256 tile, BKK=64,
// single-buffered 48 KB LDS, conflict-free XOR swizzle, global_load_lds w16,
// vmcnt(0)+syncthreads per tile, rank-1 pred fold, bf16 h/c) with exactly ONE
// change: 2D bijective XCD remap. R12/R18 grouped only jb2 per XCD -> every
// XCD streamed all 8 MB of h through its 4 MB L2 (R18 FETCH 41.2 MB vs
// unique 24 MB). R16's 2D map measured 28.9 MB. New map: XCD x owns
// jb2 in [(x&3)*4,+4) and mb in [(x>>2)*16,+16) -> ~7 MB/XCD footprint
// (Wr 2 MB + h 4 MB + c 1 MB).
// Schedule experiments R13-R18 (4-phase vmcnt(2) / burst vmcnt(0) / 1-barrier
// straight-line / BK=32 triple-buffer vmcnt(6)) all measured 51-59us —
// slower than this structure. Reverted.

#define HH 1024
#define BB 4096
#define TT 128

#define BM 128   // batch rows per block
#define BKK 64   // K tile

typedef __bf16 bf16;
typedef __bf16 v8bf __attribute__((ext_vector_type(8)));
typedef float f32x4 __attribute__((ext_vector_type(4)));

__device__ __forceinline__ float fast_sigmoid(float x) {
    return 1.0f / (1.0f + __expf(-x));
}
__device__ __forceinline__ float fast_tanh(float x) {
    return 1.0f - 2.0f / (__expf(2.0f * x) + 1.0f);
}

__device__ __forceinline__ void gload_lds16(const void* g, void* l) {
    __builtin_amdgcn_global_load_lds(
        (const __attribute__((address_space(1))) uint32_t*)(uintptr_t)g,
        (__attribute__((address_space(3))) uint32_t*)(uint32_t)(uintptr_t)l,
        16, 0, 0);
}

// ---- Prologue kernels ------------------------------------------------------

// Wr row layout: jb2*256 + g*64 + jj  <->  Whh row g*HH + jb2*64 + jj
// Wr0 = pure Whh (for t=0); Wr1 = Whh + Wih (x) Wout (for t>=1).
__global__ void prep_weights(const float* __restrict__ Whh,
                             const float* __restrict__ bih,
                             const float* __restrict__ bhh,
                             const float* __restrict__ Wih,
                             const float* __restrict__ Wout,
                             const float* __restrict__ bout,
                             bf16* __restrict__ Wr0, bf16* __restrict__ Wr1,
                             float* __restrict__ bias0, float* __restrict__ bias1) {
    int idx = blockIdx.x * blockDim.x + threadIdx.x;
    if (idx < 4 * HH * HH) {
        int k   = idx & (HH - 1);
        int row = idx >> 10;
        int jb2 = row >> 8;
        int g   = (row >> 6) & 3;
        int jj  = row & 63;
        int srow = g * HH + jb2 * 64 + jj;
        float wv = Whh[srow * HH + k];
        Wr0[idx] = (bf16)wv;
        Wr1[idx] = (bf16)(wv + Wih[srow] * Wout[k]);
    }
    if (idx < 4 * HH) {
        float b = bih[idx] + bhh[idx];
        bias0[idx] = b;
        bias1[idx] = b + Wih[idx] * bout[0];
    }
}

__global__ void prep_h(const float* __restrict__ h0, bf16* __restrict__ hb) {
    int idx = blockIdx.x * blockDim.x + threadIdx.x;
    if (idx < BB * HH) hb[idx] = (bf16)h0[idx];
}

__global__ void prep_c(const float* __restrict__ c0, bf16* __restrict__ cb) {
    int idx = blockIdx.x * blockDim.x + threadIdx.x;
    if (idx < BB * HH) cb[idx] = (bf16)c0[idx];
}

// all pred slots = b_out; atomics add the raw dot on top
__global__ void prep_pred(float* __restrict__ predbuf, const float* __restrict__ b_out) {
    int idx = blockIdx.x * blockDim.x + threadIdx.x;
    if (idx < (TT + 1) * BB) predbuf[idx] = b_out[0];
}

// ---- Per-step fused GEMM + cell update ------------------------------------
// 512 blocks = 16 jb2 x 32 mb, 2D-XCD-mapped. Block tile: 128 batch x 256
// weight rows. Wave (waveM, waveN): 64 batch x 128 wrows; acc[mi][g*2+jh].

__global__ __launch_bounds__(256, 2)
void lstm_step(const bf16* __restrict__ hread, bf16* __restrict__ hwrite,
               bf16* __restrict__ cbuf,
               const bf16* __restrict__ Wr, const float* __restrict__ biasp,
               const float* __restrict__ Wout, float* __restrict__ predbuf_w) {
    // unpadded 128-B rows, XOR-swizzled: phys 16B-chunk = logical ^ (row&7)
    __shared__ bf16 As[BM][BKK];        // h tile: 128 x 64      (16 KB)
    __shared__ bf16 Bs[2 * BM][BKK];    // weights: 256 x 64     (32 KB)

    const int tid   = threadIdx.x;
    const int lane  = tid & 63;
    const int w     = tid >> 6;
    const int waveM = w >> 1, waveN = w & 1;
    const int quad  = lane >> 4, l15 = lane & 15;

    // 2D bijective XCD remap: XCD x owns jb2 in [(x&3)*4,+4),
    // mb in [(x>>2)*16,+16).  (xcd&3,loc&3)->jb2, (xcd>>2,loc>>2)->mb.
    const int bid = blockIdx.x;
    const int xcd = bid & 7, loc = bid >> 3;        // loc 0..63
    const int jb2 = (xcd & 3) * 4 + (loc & 3);      // 0..15 weight group
    const int blockB = ((xcd >> 2) * 16 + (loc >> 2)) * BM;  // batch base

    const bf16* Asrc = hread + (size_t)blockB * HH;
    const bf16* Bsrc = Wr + (size_t)jb2 * 256 * HH;

    const int r8  = lane >> 3;        // 0..7
    const int gc  = (lane & 7) ^ r8;  // swizzled global 16B-chunk for staging
    const int swr = l15 & 7;          // read-side swizzle key (row & 7)

    // epilogue constants; bias folded into acc init
    float bsvv[2][4], wov[2];
#pragma unroll
    for (int jh = 0; jh < 2; jh++) {
        const int j = jb2 * 64 + waveN * 32 + jh * 16 + l15;
#pragma unroll
        for (int g = 0; g < 4; g++) bsvv[jh][g] = biasp[g * HH + j];
        wov[jh] = Wout[j];
    }

    f32x4 acc[4][8]; // [m-tile][gate*2 + j-half], bias-initialized
#pragma unroll
    for (int mi = 0; mi < 4; mi++)
#pragma unroll
        for (int g = 0; g < 4; g++)
#pragma unroll
            for (int jh = 0; jh < 2; jh++) {
                const float bv = bsvv[jh][g];
                acc[mi][g * 2 + jh] = (f32x4){bv, bv, bv, bv};
            }

    for (int k0 = 0; k0 < HH; k0 += BKK) {
        // A: wave stages rows [w*32, w*32+32) — 4 calls (8 rows x 128 B each)
#pragma unroll
        for (int c2 = 0; c2 < 4; c2++) {
            const int rowb = w * 32 + c2 * 8;
            gload_lds16(Asrc + (size_t)(rowb + r8) * HH + k0 + gc * 8, &As[rowb][0]);
        }
        // B: wave stages rows [w*64, w*64+64) — 8 calls
#pragma unroll
        for (int c2 = 0; c2 < 8; c2++) {
            const int rowb = w * 64 + c2 * 8;
            gload_lds16(Bsrc + (size_t)(rowb + r8) * HH + k0 + gc * 8, &Bs[rowb][0]);
        }
        asm volatile("s_waitcnt vmcnt(0)" ::: "memory");
        __syncthreads();
#pragma unroll
        for (int kk = 0; kk < 2; kk++) {
            v8bf a[4], b[8];
            const int pch = ((kk * 4 + quad) ^ swr) * 8;
#pragma unroll
            for (int mi = 0; mi < 4; mi++)
                a[mi] = *(const v8bf*)&As[waveM * 64 + mi * 16 + l15][pch];
#pragma unroll
            for (int g = 0; g < 4; g++)
#pragma unroll
                for (int jh = 0; jh < 2; jh++)
                    b[g * 2 + jh] =
                        *(const v8bf*)&Bs[g * 64 + waveN * 32 + jh * 16 + l15][pch];
#pragma unroll
            for (int mi = 0; mi < 4; mi++)
#pragma unroll
                for (int nt = 0; nt < 8; nt++)
                    acc[mi][nt] = __builtin_amdgcn_mfma_f32_16x16x32_bf16(
                        a[mi], b[nt], acc[mi][nt], 0, 0, 0);
        }
        __syncthreads();
    }

    // Epilogue: acc[mi][g*2+jh][r] = gate g (bias incl.) at (batch, j):
    //   batch = blockB + waveM*64 + mi*16 + quad*4 + r
    //   j     = jb2*64 + waveN*32 + jh*16 + l15
#pragma unroll
    for (int mi = 0; mi < 4; mi++) {
#pragma unroll
        for (int r = 0; r < 4; r++) {
            const int b = blockB + waveM * 64 + mi * 16 + quad * 4 + r;
            float pacc = 0.0f;
#pragma unroll
            for (int jh = 0; jh < 2; jh++) {
                const int j = jb2 * 64 + waveN * 32 + jh * 16 + l15;
                const float gi = acc[mi][0 + jh][r];
                const float gf = acc[mi][2 + jh][r];
                const float gg = acc[mi][4 + jh][r];
                const float go = acc[mi][6 + jh][r];
                const float cprev = (float)cbuf[(size_t)b * HH + j];
                const float cn = fast_sigmoid(gf) * cprev
                               + fast_sigmoid(gi) * fast_tanh(gg);
                cbuf[(size_t)b * HH + j] = (bf16)cn;   // in-place, 1 owner/elem
                const float hn = fast_sigmoid(go) * fast_tanh(cn);
                hwrite[(size_t)b * HH + j] = (bf16)hn;
                pacc += hn * wov[jh];
            }
            pacc += __shfl_xor(pacc, 1);
            pacc += __shfl_xor(pacc, 2);
            pacc += __shfl_xor(pacc, 4);
            pacc += __shfl_xor(pacc, 8);
            if (l15 == 0) atomicAdd(&predbuf_w[b], pacc);
        }
    }
}

// ---- Output transpose: out[b][t] = pred_t[b] ------------------------------

__global__ void write_out(const float* __restrict__ predbuf, float* __restrict__ out) {
    int idx = blockIdx.x * blockDim.x + threadIdx.x;
    if (idx < BB * TT) {
        int t = idx & (TT - 1);
        int b = idx >> 7;
        out[idx] = predbuf[(size_t)(t + 1) * BB + b];
    }
}

// ---- Host launch -----------------------------------------------------------

extern "C" void kernel_launch(void* const* d_in, const int* in_sizes, int n_in,
                              void* d_out, int out_size, void* d_ws, size_t ws_size,
                              hipStream_t stream) {
    const float* hidden = (const float*)d_in[0];
    const float* cell   = (const float*)d_in[1];
    const float* Wih    = (const float*)d_in[2];
    const float* Whh    = (const float*)d_in[3];
    const float* bih    = (const float*)d_in[4];
    const float* bhh    = (const float*)d_in[5];
    const float* Wout   = (const float*)d_in[6];
    const float* bout   = (const float*)d_in[7];
    float* out = (float*)d_out;

    char* ws = (char*)d_ws;
    bf16* Wr0 = (bf16*)ws;       ws += (size_t)4 * HH * HH * 2;   // 8 MB
    bf16* Wr1 = (bf16*)ws;       ws += (size_t)4 * HH * HH * 2;   // 8 MB
    bf16* hb0 = (bf16*)ws;       ws += (size_t)BB * HH * 2;       // 8 MB
    bf16* hb1 = (bf16*)ws;       ws += (size_t)BB * HH * 2;       // 8 MB
    bf16* cbuf = (bf16*)ws;      ws += (size_t)BB * HH * 2;       // 8 MB
    float* bias0 = (float*)ws;   ws += (size_t)4 * HH * 4;        // 16 KB
    float* bias1 = (float*)ws;   ws += (size_t)4 * HH * 4;        // 16 KB
    float* predbuf = (float*)ws; ws += (size_t)(TT + 1) * BB * 4; // 2.1 MB

    prep_weights<<<(4 * HH * HH + 255) / 256, 256, 0, stream>>>(
        Whh, bih, bhh, Wih, Wout, bout, Wr0, Wr1, bias0, bias1);
    prep_h<<<(BB * HH + 255) / 256, 256, 0, stream>>>(hidden, hb0);
    prep_c<<<(BB * HH + 255) / 256, 256, 0, stream>>>(cell, cbuf);
    prep_pred<<<((TT + 1) * BB + 255) / 256, 256, 0, stream>>>(predbuf, bout);

    bf16* hb[2] = {hb0, hb1};
    for (int t = 0; t < TT; t++) {
        const bf16* hr = hb[t & 1];
        bf16* hw = hb[(t + 1) & 1];
        const bf16* Wr   = (t == 0) ? Wr0 : Wr1;
        const float* bsp = (t == 0) ? bias0 : bias1;
        lstm_step<<<512, 256, 0, stream>>>(
            hr, hw, cbuf, Wr, bsp, Wout, predbuf + (size_t)(t + 1) * BB);
    }

    write_out<<<(BB * TT + 255) / 256, 256, 0, stream>>>(predbuf, out);
}